// Round 1
// baseline (175.647 us; speedup 1.0000x reference)
//
#include <hip/hip_runtime.h>
#include <stdint.h>

#define K_DIM 1024
#define N_DIM 1024
#define BM 128
#define BN 128
#define BK 32

typedef __attribute__((ext_vector_type(4))) float f32x4;
typedef __attribute__((ext_vector_type(8))) short bf16x8;
typedef __attribute__((ext_vector_type(4))) uint32_t u32x4;

// round-half-up to bf16 and pack two: low 16 = a, high 16 = b
__device__ __forceinline__ uint32_t pack_bf16(float a, float b) {
  uint32_t ua = __builtin_bit_cast(uint32_t, a) + 0x8000u;
  uint32_t ub = __builtin_bit_cast(uint32_t, b) + 0x8000u;
  return __builtin_amdgcn_perm(ub, ua, 0x07060302u);  // {ub[3],ub[2],ua[3],ua[2]}
}

__device__ __forceinline__ f32x4 wbin4(f32x4 v, float kkv, float aav) {
  f32x4 r;
#pragma unroll
  for (int i = 0; i < 4; ++i) {
    float t = v[i] * kkv;
    t = fminf(fmaxf(t, -1.0f), 1.0f);
    r[i] = t * aav;
  }
  return r;
}

// C tile 128x128 per block; 4 waves in 2x2; each wave 64x64 = 4x4 frags of 16x16.
// LDS tiles [128 rows][32 bf16] = row stride 64B = 4 slots of 16B.
// Swizzle: phys_slot = slot ^ ((row>>1)&3)  -> 2-way LDS access (free).
__global__ __launch_bounds__(256, 2) void binlin_gemm(
    const float* __restrict__ x, const float* __restrict__ w,
    const float* __restrict__ bias, const float* __restrict__ kkp,
    const float* __restrict__ aap, float* __restrict__ out) {
  __shared__ uint32_t lA[BM * 16];  // 8 KB
  __shared__ uint32_t lB[BN * 16];  // 8 KB

  const int tid = threadIdx.x;
  const int bid = blockIdx.x;
  const int nIdx = bid & 7;   // N_DIM / BN = 8 (n-fastest: 8 consecutive blocks share x panel)
  const int mIdx = bid >> 3;
  const int row0 = mIdx * BM;
  const int col0 = nIdx * BN;

  const float kkv = kkp[0];
  const float aav = aap[0];

  // staging assignment: thread t -> row r = t>>1, 16-float half h = t&1
  const int r = tid >> 1;
  const int h = tid & 1;
  const int sw = (r >> 1) & 3;
  const int s0 = h * 2;

  const float* ga = x + (size_t)(row0 + r) * K_DIM + h * 16;
  const float* gb = w + (size_t)(col0 + r) * K_DIM + h * 16;
  uint32_t* lap = lA + r * 16;
  uint32_t* lbp = lB + r * 16;

  const int wid = tid >> 6;
  const int wr = wid >> 1;
  const int wc = wid & 1;
  const int lane = tid & 63;
  const int cl = lane & 15;   // fragment row/col within 16
  const int kg = lane >> 4;   // k-group: elems kg*8 .. kg*8+7 = 16B slot kg

  f32x4 acc[4][4] = {};

  for (int kt = 0; kt < K_DIM / BK; ++kt) {
    // ---- global loads (overlap with previous iteration's MFMA) ----
    const f32x4* pa = (const f32x4*)(ga + kt * BK);
    const f32x4* pb = (const f32x4*)(gb + kt * BK);
    f32x4 a0 = pa[0], a1 = pa[1], a2 = pa[2], a3 = pa[3];
    f32x4 b0 = pb[0], b1 = pb[1], b2 = pb[2], b3 = pb[3];

    b0 = wbin4(b0, kkv, aav);
    b1 = wbin4(b1, kkv, aav);
    b2 = wbin4(b2, kkv, aav);
    b3 = wbin4(b3, kkv, aav);

    u32x4 ca0 = {pack_bf16(a0[0], a0[1]), pack_bf16(a0[2], a0[3]),
                 pack_bf16(a1[0], a1[1]), pack_bf16(a1[2], a1[3])};
    u32x4 ca1 = {pack_bf16(a2[0], a2[1]), pack_bf16(a2[2], a2[3]),
                 pack_bf16(a3[0], a3[1]), pack_bf16(a3[2], a3[3])};
    u32x4 cb0 = {pack_bf16(b0[0], b0[1]), pack_bf16(b0[2], b0[3]),
                 pack_bf16(b1[0], b1[1]), pack_bf16(b1[2], b1[3])};
    u32x4 cb1 = {pack_bf16(b2[0], b2[1]), pack_bf16(b2[2], b2[3]),
                 pack_bf16(b3[0], b3[1]), pack_bf16(b3[2], b3[3])};

    __syncthreads();  // previous iteration's LDS reads complete
    *(u32x4*)(lap + ((s0 ^ sw) * 4)) = ca0;
    *(u32x4*)(lap + (((s0 + 1) ^ sw) * 4)) = ca1;
    *(u32x4*)(lbp + ((s0 ^ sw) * 4)) = cb0;
    *(u32x4*)(lbp + (((s0 + 1) ^ sw) * 4)) = cb1;
    __syncthreads();  // tile ready

    bf16x8 af[4], bfr[4];
#pragma unroll
    for (int m = 0; m < 4; ++m) {
      int rr = wr * 64 + m * 16 + cl;
      af[m] = *(const bf16x8*)(lA + rr * 16 + ((kg ^ ((rr >> 1) & 3)) * 4));
    }
#pragma unroll
    for (int n = 0; n < 4; ++n) {
      int rr = wc * 64 + n * 16 + cl;
      bfr[n] = *(const bf16x8*)(lB + rr * 16 + ((kg ^ ((rr >> 1) & 3)) * 4));
    }
#pragma unroll
    for (int m = 0; m < 4; ++m)
#pragma unroll
      for (int n = 0; n < 4; ++n)
        acc[m][n] = __builtin_amdgcn_mfma_f32_16x16x32_bf16(af[m], bfr[n],
                                                            acc[m][n], 0, 0, 0);
  }

  // ---- epilogue: bias + fp32 store ----
#pragma unroll
  for (int n = 0; n < 4; ++n) {
    int col = col0 + wc * 64 + n * 16 + cl;
    float bv = bias[col];
#pragma unroll
    for (int m = 0; m < 4; ++m) {
      int rowb = row0 + wr * 64 + m * 16 + kg * 4;
#pragma unroll
      for (int i = 0; i < 4; ++i) {
        out[(size_t)(rowb + i) * N_DIM + col] = acc[m][n][i] + bv;
      }
    }
  }
}

extern "C" void kernel_launch(void* const* d_in, const int* in_sizes, int n_in,
                              void* d_out, int out_size, void* d_ws, size_t ws_size,
                              hipStream_t stream) {
  const float* x = (const float*)d_in[0];
  const float* w = (const float*)d_in[1];
  const float* bias = (const float*)d_in[2];
  const float* kk = (const float*)d_in[3];
  const float* aa = (const float*)d_in[4];
  float* out = (float*)d_out;

  const int M = in_sizes[0] / K_DIM;          // 32768
  const int grid = (M / BM) * (N_DIM / BN);   // 256 * 8 = 2048
  binlin_gemm<<<grid, 256, 0, stream>>>(x, w, bias, kk, aa, out);
}